// Round 3
// baseline (868.266 us; speedup 1.0000x reference)
//
#include <hip/hip_runtime.h>

#define H_    32
#define KVH_  8
#define HD_   128
#define CHUNK_ 2048
#define BQ    128
#define BK    64
#define LKS   136   // lK row stride (ushorts)
#define LVS   72    // lV row stride
#define LPS   68    // lP row stride (overlaid on lK: 4*32*68 = 8704 = 64*136 exactly)

typedef short bf16x8 __attribute__((ext_vector_type(8)));
typedef float f32x4  __attribute__((ext_vector_type(4)));

__device__ __forceinline__ ushort f2bf(float x) {
  unsigned u = __builtin_bit_cast(unsigned, x);
  u += 0x7FFFu + ((u >> 16) & 1u);     // RNE
  return (ushort)(u >> 16);
}
__device__ __forceinline__ bf16x8 pack8(float4 a, float4 b) {
  bf16x8 r;
  r[0] = (short)f2bf(a.x); r[1] = (short)f2bf(a.y); r[2] = (short)f2bf(a.z); r[3] = (short)f2bf(a.w);
  r[4] = (short)f2bf(b.x); r[5] = (short)f2bf(b.y); r[6] = (short)f2bf(b.z); r[7] = (short)f2bf(b.w);
  return r;
}

// ---------- fill_k: kc [T][KVH][HD] fp32 (t < CHUNK) -> Kb [KVH][T][HD] bf16 ----------
__global__ void fill_k(const float* __restrict__ kc, ushort* __restrict__ Kb, int T) {
  int idx = blockIdx.x * 256 + threadIdx.x;   // 8-element chunk
  int e = idx << 3;
  int t = e >> 10, kvh = (e >> 7) & 7, d = e & 127;
  const float* s = kc + ((size_t)t * KVH_ + kvh) * HD_ + d;
  *(bf16x8*)&Kb[((size_t)kvh * T + t) * HD_ + d] =
      pack8(*(const float4*)s, *(const float4*)(s + 4));
}

// ---------- fill_v: vc [T][KVH][HD] fp32 (t < CHUNK) -> Vt [KVH][HD][T] bf16 ----------
__global__ void fill_v(const float* __restrict__ vc, ushort* __restrict__ Vt, int T) {
  __shared__ ushort tile[64 * 128];   // [t][d]
  int t0  = blockIdx.x * 64;
  int kvh = blockIdx.y;
  int tid = threadIdx.x;
  int tr = tid >> 5, c4 = tid & 31;
#pragma unroll
  for (int it = 0; it < 8; ++it) {
    int t = it * 8 + tr;
    float4 x = *(const float4*)&vc[(((size_t)(t0 + t) * KVH_ + kvh) << 7) + (c4 << 2)];
    ushort4 y = make_ushort4(f2bf(x.x), f2bf(x.y), f2bf(x.z), f2bf(x.w));
    *(ushort4*)&tile[t * 128 + (c4 << 2)] = y;
  }
  __syncthreads();
  int d = tid >> 1, half = tid & 1;
  unsigned wb[16];
#pragma unroll
  for (int j = 0; j < 16; ++j) {
    unsigned lo = tile[(half * 32 + 2 * j) * 128 + d];
    unsigned hi = tile[(half * 32 + 2 * j + 1) * 128 + d];
    wb[j] = lo | (hi << 16);
  }
  uint4* dst = (uint4*)&Vt[((size_t)(kvh * 128 + d)) * T + t0 + half * 32];
  dst[0] = make_uint4(wb[0],  wb[1],  wb[2],  wb[3]);
  dst[1] = make_uint4(wb[4],  wb[5],  wb[6],  wb[7]);
  dst[2] = make_uint4(wb[8],  wb[9],  wb[10], wb[11]);
  dst[3] = make_uint4(wb[12], wb[13], wb[14], wb[15]);
}

// ---------- scatter_new: k,v [N][KVH][HD] fp32 -> Kb rows / Vt cols at slot_mapping ----
__global__ void scatter_new(const float* __restrict__ k, const float* __restrict__ v,
                            const int* __restrict__ slots,
                            ushort* __restrict__ Kb, ushort* __restrict__ Vt, int T) {
  __shared__ ushort tile[64 * 128];
  __shared__ int sl[64];
  __shared__ int contig;
  int r0  = blockIdx.x * 64;
  int kvh = blockIdx.y;
  int tid = threadIdx.x;
  if (tid < 64) sl[tid] = slots[r0 + tid];
  if (tid == 0) contig = 0;
  __syncthreads();
  // K rows (honor slots) + V tile load
#pragma unroll
  for (int i = tid; i < 1024; i += 256) {
    int r = i >> 4, d = (i & 15) << 3;
    const float* ks = k + ((size_t)(r0 + r) * KVH_ + kvh) * HD_ + d;
    *(bf16x8*)&Kb[((size_t)kvh * T + sl[r]) * HD_ + d] =
        pack8(*(const float4*)ks, *(const float4*)(ks + 4));
    const float* vs = v + ((size_t)(r0 + r) * KVH_ + kvh) * HD_ + d;
    *(bf16x8*)&tile[r * 128 + d] = pack8(*(const float4*)vs, *(const float4*)(vs + 4));
  }
  if (tid < 64) {
    bool ok = (tid == 63) || (sl[tid + 1] == sl[tid] + 1);
    unsigned long long b = __ballot(ok);
    if (tid == 0 && b == ~0ull) contig = 1;
  }
  __syncthreads();
  int d = tid >> 1, half = tid & 1;
  if (contig) {
    int t0 = sl[0];
    unsigned wb[16];
#pragma unroll
    for (int j = 0; j < 16; ++j) {
      unsigned lo = tile[(half * 32 + 2 * j) * 128 + d];
      unsigned hi = tile[(half * 32 + 2 * j + 1) * 128 + d];
      wb[j] = lo | (hi << 16);
    }
    uint4* dst = (uint4*)&Vt[((size_t)(kvh * 128 + d)) * T + t0 + half * 32];
    dst[0] = make_uint4(wb[0],  wb[1],  wb[2],  wb[3]);
    dst[1] = make_uint4(wb[4],  wb[5],  wb[6],  wb[7]);
    dst[2] = make_uint4(wb[8],  wb[9],  wb[10], wb[11]);
    dst[3] = make_uint4(wb[12], wb[13], wb[14], wb[15]);
  } else {
    for (int j = 0; j < 32; ++j) {
      int r = half * 32 + j;
      Vt[((size_t)(kvh * 128 + d)) * T + sl[r]] = tile[r * 128 + d];
    }
  }
}

// ---------- fa_kernel: swapped-operand flash attention, STRIDED kv-split x2 ----------
// grid (H, nq, 2); block 256 = 4 waves; wave w: 32 queries [q0+32w, q0+32w+32)
// parity p processes tiles it = p, p+2, p+4, ... -> both parities march in lockstep
// (tight L2 window, unlike contiguous split which scattered start positions).
__global__ __launch_bounds__(256, 4)
void fa_kernel(const float* __restrict__ q, const ushort* __restrict__ Kb,
               const ushort* __restrict__ Vt, float* __restrict__ O0,
               float* __restrict__ O1, float* __restrict__ ML,
               int N, int T) {
  __shared__ ushort smem[64 * LKS + 128 * LVS];   // 35840 B
  ushort* lK = smem;
  ushort* lV = smem + 64 * LKS;

  int h  = blockIdx.x;
  int qt = blockIdx.y;
  int p  = blockIdx.z;
  int q0 = qt * BQ;
  int kvh = h >> 2;
  int tid = threadIdx.x, w = tid >> 6, lane = tid & 63;
  int quad = lane >> 4, l16 = lane & 15;
  ushort* lP = smem + w * (32 * LPS);   // wave-private, overlays lK

  int ntb = (CHUNK_ + q0 + BQ) >> 6;    // always even

  // Q B-frags straight from fp32 global (once per kernel)
  bf16x8 qf[2][4];
  {
    const float* qb = q + ((size_t)(q0 + 32 * w + l16) * H_ + h) * HD_;
#pragma unroll
    for (int nt = 0; nt < 2; ++nt)
#pragma unroll
      for (int kt = 0; kt < 4; ++kt) {
        const float* s = qb + nt * 16 * H_ * HD_ + kt * 32 + quad * 8;
        qf[nt][kt] = pack8(*(const float4*)s, *(const float4*)(s + 4));
      }
  }

  f32x4 o[2][8];
  float m[2] = {-1e30f, -1e30f}, l[2] = {0.f, 0.f};
#pragma unroll
  for (int nt = 0; nt < 2; ++nt)
#pragma unroll
    for (int d8 = 0; d8 < 8; ++d8) o[nt][d8] = f32x4{0.f, 0.f, 0.f, 0.f};
  const float sc = 0.08838834764831845f * 1.4426950408889634f;  // SCALE*log2e
  int qpos0 = CHUNK_ + q0 + 32 * w + l16;

  for (int it = p; it < ntb; it += 2) {
    int t0 = it << 6;
    {
      const ushort* src = Kb + ((size_t)kvh * T + t0) * HD_;
#pragma unroll
      for (int i = tid; i < 1024; i += 256) {
        int r = i >> 4, c = (i & 15) << 3;
        *(bf16x8*)&lK[r * LKS + c] = *(const bf16x8*)(src + r * HD_ + c);
      }
      const ushort* vsrc = Vt + ((size_t)kvh * HD_) * T + t0;
#pragma unroll
      for (int i = tid; i < 1024; i += 256) {
        int d = i >> 3, c = (i & 7) << 3;
        *(bf16x8*)&lV[d * LVS + c] = *(const bf16x8*)(vsrc + (size_t)d * T + c);
      }
    }
    __syncthreads();                               // A: staging visible

    bool active = (t0 <= CHUNK_ + q0 + 32 * w + 31);
    uint2 pw[2][4];
    if (active) {
      f32x4 s_[4][2];
#pragma unroll
      for (int tt = 0; tt < 4; ++tt)
#pragma unroll
        for (int nt = 0; nt < 2; ++nt) s_[tt][nt] = f32x4{0.f, 0.f, 0.f, 0.f};
#pragma unroll
      for (int tt = 0; tt < 4; ++tt) {
        bf16x8 kf[4];
#pragma unroll
        for (int kt = 0; kt < 4; ++kt)
          kf[kt] = *(const bf16x8*)&lK[(l16 + 16 * tt) * LKS + kt * 32 + quad * 8];
#pragma unroll
        for (int nt = 0; nt < 2; ++nt)
#pragma unroll
          for (int kt = 0; kt < 4; ++kt)
            s_[tt][nt] = __builtin_amdgcn_mfma_f32_16x16x32_bf16(kf[kt], qf[nt][kt], s_[tt][nt], 0, 0, 0);
      }
      bool need_mask = (t0 + BK - 1) > (CHUNK_ + q0 + 32 * w);
#pragma unroll
      for (int nt = 0; nt < 2; ++nt) {
        int qp = qpos0 + nt * 16;
        float mx = -3.0e38f;
#pragma unroll
        for (int tt = 0; tt < 4; ++tt)
#pragma unroll
          for (int r = 0; r < 4; ++r) {
            float sv = s_[tt][nt][r] * sc;
            if (need_mask) {
              int t = t0 + tt * 16 + quad * 4 + r;
              sv = (t > qp) ? -3.0e38f : sv;
            }
            s_[tt][nt][r] = sv;
            mx = fmaxf(mx, sv);
          }
        mx = fmaxf(mx, __shfl_xor(mx, 16));
        mx = fmaxf(mx, __shfl_xor(mx, 32));
        float mnew  = fmaxf(m[nt], mx);
        float alpha = exp2f(m[nt] - mnew);
        m[nt] = mnew;
        float sum = 0.f;
#pragma unroll
        for (int tt = 0; tt < 4; ++tt) {
          f32x4 pv;
#pragma unroll
          for (int r = 0; r < 4; ++r) {
            float pe = exp2f(s_[tt][nt][r] - mnew);
            pv[r] = pe;
            sum += pe;
          }
          uint2 u;
          u.x = (unsigned)f2bf(pv[0]) | ((unsigned)f2bf(pv[1]) << 16);
          u.y = (unsigned)f2bf(pv[2]) | ((unsigned)f2bf(pv[3]) << 16);
          pw[nt][tt] = u;
        }
        sum += __shfl_xor(sum, 16);
        sum += __shfl_xor(sum, 32);
        l[nt] = l[nt] * alpha + sum;
#pragma unroll
        for (int d8 = 0; d8 < 8; ++d8) o[nt][d8] *= alpha;
      }
    }
    __syncthreads();                               // B: all lK reads done

    if (active) {
#pragma unroll
      for (int nt = 0; nt < 2; ++nt)
#pragma unroll
        for (int tt = 0; tt < 4; ++tt)
          *(uint2*)&lP[(nt * 16 + l16) * LPS + tt * 16 + quad * 4] = pw[nt][tt];
      bf16x8 pf[2][2];
#pragma unroll
      for (int nt = 0; nt < 2; ++nt)
#pragma unroll
        for (int kt2 = 0; kt2 < 2; ++kt2) {
          int off = (nt * 16 + l16) * LPS + kt2 * 32 + quad * 8;
          uint2 a = *(const uint2*)&lP[off];
          uint2 b = *(const uint2*)&lP[off + 4];
          uint4 u = make_uint4(a.x, a.y, b.x, b.y);
          pf[nt][kt2] = __builtin_bit_cast(bf16x8, u);
        }
#pragma unroll
      for (int d8 = 0; d8 < 8; ++d8) {
        bf16x8 vf[2];
#pragma unroll
        for (int kt2 = 0; kt2 < 2; ++kt2)
          vf[kt2] = *(const bf16x8*)&lV[(d8 * 16 + l16) * LVS + kt2 * 32 + quad * 8];
#pragma unroll
        for (int nt = 0; nt < 2; ++nt)
#pragma unroll
          for (int kt2 = 0; kt2 < 2; ++kt2)
            o[nt][d8] = __builtin_amdgcn_mfma_f32_16x16x32_bf16(vf[kt2], pf[nt][kt2], o[nt][d8], 0, 0, 0);
      }
    }
    __syncthreads();                               // C: lP/lV reads done
  }

  // epilogue: normalized partial + (m,l)
  float* OUT = p ? O1 : O0;
#pragma unroll
  for (int nt = 0; nt < 2; ++nt) {
    int qg = q0 + 32 * w + nt * 16 + l16;
    float invl = 1.0f / l[nt];
#pragma unroll
    for (int d8 = 0; d8 < 8; ++d8) {
      f32x4 r = o[nt][d8] * invl;
      *(float4*)&OUT[((size_t)qg * H_ + h) * HD_ + d8 * 16 + quad * 4] =
          make_float4(r[0], r[1], r[2], r[3]);
    }
    if (quad == 0) {
      float* mlp = ML + ((size_t)qg * H_ + h) * 4 + p * 2;
      mlp[0] = m[nt];
      mlp[1] = l[nt];
    }
  }
}

// ---------- combine: out = (w0*o0 + w1*o1) with w_p = exp2(m_p - m) * l_p ----------
__global__ void combine(float* __restrict__ out, const float* __restrict__ O1,
                        const float* __restrict__ ML) {
  int idx = blockIdx.x * 256 + threadIdx.x;   // float4 index
  int qh = idx >> 5;                          // 32 float4 per (q,h)
  float4 o0 = ((const float4*)out)[idx];
  float4 o1 = ((const float4*)O1)[idx];
  float m0 = ML[qh * 4 + 0], l0 = ML[qh * 4 + 1];
  float m1 = ML[qh * 4 + 2], l1 = ML[qh * 4 + 3];
  float m  = fmaxf(m0, m1);
  float w0 = exp2f(m0 - m) * l0;
  float w1 = exp2f(m1 - m) * l1;
  float inv = 1.0f / (w0 + w1);
  w0 *= inv; w1 *= inv;
  ((float4*)out)[idx] = make_float4(o0.x * w0 + o1.x * w1, o0.y * w0 + o1.y * w1,
                                    o0.z * w0 + o1.z * w1, o0.w * w0 + o1.w * w1);
}

extern "C" void kernel_launch(void* const* d_in, const int* in_sizes, int n_in,
                              void* d_out, int out_size, void* d_ws, size_t ws_size,
                              hipStream_t stream) {
  const float* q  = (const float*)d_in[0];
  const float* k  = (const float*)d_in[1];
  const float* v  = (const float*)d_in[2];
  const float* kc = (const float*)d_in[3];
  const float* vc = (const float*)d_in[4];
  const int* slots = (const int*)d_in[5];

  int N = in_sizes[5];
  int T = CHUNK_ + N;
  int nq = N / BQ;

  ushort* Kb = (ushort*)d_ws;                              // [KVH][T][HD]
  ushort* Vt = Kb + (size_t)KVH_ * T * HD_;                // [KVH][HD][T]
  float*  O1 = (float*)(Vt + (size_t)KVH_ * HD_ * T);      // [N][H][HD]
  float*  ML = O1 + (size_t)N * H_ * HD_;                  // [N*H][4]
  float* out = (float*)d_out;

  fill_k<<<(CHUNK_ * KVH_ * HD_) / 2048, 256, 0, stream>>>(kc, Kb, T);
  fill_v<<<dim3(CHUNK_ / 64, KVH_), 256, 0, stream>>>(vc, Vt, T);
  scatter_new<<<dim3(N / 64, KVH_), 256, 0, stream>>>(k, v, slots, Kb, Vt, T);
  fa_kernel<<<dim3(H_, nq, 2), 256, 0, stream>>>(q, Kb, Vt, out, O1, ML, N, T);
  combine<<<(N * H_ * HD_) / 1024, 256, 0, stream>>>(out, O1, ML);
}

// Round 4
// 557.613 us; speedup vs baseline: 1.5571x; 1.5571x over previous
//
#include <hip/hip_runtime.h>

#define H_    32
#define KVH_  8
#define HD_   128
#define CHUNK_ 2048
#define BQ    128
#define BK    64
#define LKS   136   // lK row stride (ushorts)
#define LVS   72    // lV row stride
#define LPS   68    // lP row stride (overlaid on lK: 4*32*68 = 8704 = 64*136 exactly)

typedef short bf16x8 __attribute__((ext_vector_type(8)));
typedef float f32x4  __attribute__((ext_vector_type(4)));

__device__ __forceinline__ ushort f2bf(float x) {
  unsigned u = __builtin_bit_cast(unsigned, x);
  u += 0x7FFFu + ((u >> 16) & 1u);     // RNE
  return (ushort)(u >> 16);
}
__device__ __forceinline__ bf16x8 pack8(float4 a, float4 b) {
  bf16x8 r;
  r[0] = (short)f2bf(a.x); r[1] = (short)f2bf(a.y); r[2] = (short)f2bf(a.z); r[3] = (short)f2bf(a.w);
  r[4] = (short)f2bf(b.x); r[5] = (short)f2bf(b.y); r[6] = (short)f2bf(b.z); r[7] = (short)f2bf(b.w);
  return r;
}

// ---------- prep: build Kb [KVH][T][HD] and Vt [KVH][HD][T] (bf16) in one pass ----
// grid (T/64, KVH). Blocks with t0 < CHUNK convert from kc/vc (dest t == src t);
// blocks with t0 >= CHUNK convert new k/v rows, scattering to slot_mapping.
__global__ void prep(const float* __restrict__ kc, const float* __restrict__ vc,
                     const float* __restrict__ k, const float* __restrict__ v,
                     const int* __restrict__ slots,
                     ushort* __restrict__ Kb, ushort* __restrict__ Vt, int T) {
  __shared__ ushort tile[64 * 128];
  __shared__ int sl[64];
  __shared__ int contig;
  int t0  = blockIdx.x * 64;
  int kvh = blockIdx.y;
  int tid = threadIdx.x;
  bool isnew = (t0 >= CHUNK_);
  if (isnew) {
    if (tid < 64) sl[tid] = slots[t0 - CHUNK_ + tid];
    if (tid == 0) contig = 0;
    __syncthreads();
    if (tid < 64) {
      bool ok = (tid == 63) || (sl[tid + 1] == sl[tid] + 1);
      unsigned long long b = __ballot(ok);
      if (tid == 0 && b == ~0ull) contig = 1;
    }
  }
#pragma unroll
  for (int i = tid; i < 1024; i += 256) {
    int r = i >> 4, d = (i & 15) << 3;
    const float* ks;
    const float* vs;
    int dstT;
    if (isnew) {
      int rr = t0 - CHUNK_ + r;
      ks = k + ((size_t)rr * KVH_ + kvh) * HD_ + d;
      vs = v + ((size_t)rr * KVH_ + kvh) * HD_ + d;
      dstT = sl[r];
    } else {
      ks = kc + ((size_t)(t0 + r) * KVH_ + kvh) * HD_ + d;
      vs = vc + ((size_t)(t0 + r) * KVH_ + kvh) * HD_ + d;
      dstT = t0 + r;
    }
    *(bf16x8*)&Kb[((size_t)kvh * T + dstT) * HD_ + d] =
        pack8(*(const float4*)ks, *(const float4*)(ks + 4));
    *(bf16x8*)&tile[r * 128 + d] = pack8(*(const float4*)vs, *(const float4*)(vs + 4));
  }
  __syncthreads();
  int d = tid >> 1, half = tid & 1;
  if (!isnew || contig) {
    int tbase = isnew ? sl[0] : t0;
    unsigned wb[16];
#pragma unroll
    for (int j = 0; j < 16; ++j) {
      unsigned lo = tile[(half * 32 + 2 * j) * 128 + d];
      unsigned hi = tile[(half * 32 + 2 * j + 1) * 128 + d];
      wb[j] = lo | (hi << 16);
    }
    uint4* dst = (uint4*)&Vt[((size_t)(kvh * 128 + d)) * T + tbase + half * 32];
    dst[0] = make_uint4(wb[0],  wb[1],  wb[2],  wb[3]);
    dst[1] = make_uint4(wb[4],  wb[5],  wb[6],  wb[7]);
    dst[2] = make_uint4(wb[8],  wb[9],  wb[10], wb[11]);
    dst[3] = make_uint4(wb[12], wb[13], wb[14], wb[15]);
  } else {
    for (int j = 0; j < 32; ++j) {
      int r = half * 32 + j;
      Vt[((size_t)(kvh * 128 + d)) * T + sl[r]] = tile[r * 128 + d];
    }
  }
}

// ---------- fa_kernel: swapped-operand flash attention, strided kv-split x2 ----------
// grid (H, nq, 2); block 256 = 4 waves; wave w: 32 queries [q0+32w, q0+32w+32)
// parity p: tiles it = p, p+2, ... (lockstep L2 window). launch_bounds(256,2):
// 256-VGPR budget -> NO spill (R2/R3 regression was launch_bounds-induced scratch).
// Register prefetch: global loads for tile it+2 issue right after ds_write(it).
__global__ __launch_bounds__(256, 2)
void fa_kernel(const float* __restrict__ q, const ushort* __restrict__ Kb,
               const ushort* __restrict__ Vt, float* __restrict__ O0,
               float* __restrict__ O1, float* __restrict__ ML,
               int N, int T) {
  __shared__ ushort smem[64 * LKS + 128 * LVS];   // 35840 B
  ushort* lK = smem;
  ushort* lV = smem + 64 * LKS;

  int h  = blockIdx.x;
  int qt = blockIdx.y;
  int p  = blockIdx.z;
  int q0 = qt * BQ;
  int kvh = h >> 2;
  int tid = threadIdx.x, w = tid >> 6, lane = tid & 63;
  int quad = lane >> 4, l16 = lane & 15;
  ushort* lP = smem + w * (32 * LPS);   // wave-private, overlays lK

  int ntb = (CHUNK_ + q0 + BQ) >> 6;    // always even

  // Q B-frags straight from fp32 global (once per kernel)
  bf16x8 qf[2][4];
  {
    const float* qb = q + ((size_t)(q0 + 32 * w + l16) * H_ + h) * HD_;
#pragma unroll
    for (int nt = 0; nt < 2; ++nt)
#pragma unroll
      for (int kt = 0; kt < 4; ++kt) {
        const float* s = qb + nt * 16 * H_ * HD_ + kt * 32 + quad * 8;
        qf[nt][kt] = pack8(*(const float4*)s, *(const float4*)(s + 4));
      }
  }

  f32x4 o[2][8];
  float m[2] = {-1e30f, -1e30f}, l[2] = {0.f, 0.f};
#pragma unroll
  for (int nt = 0; nt < 2; ++nt)
#pragma unroll
    for (int d8 = 0; d8 < 8; ++d8) o[nt][d8] = f32x4{0.f, 0.f, 0.f, 0.f};
  const float sc = 0.08838834764831845f * 1.4426950408889634f;  // SCALE*log2e
  int qpos0 = CHUNK_ + q0 + 32 * w + l16;

  const ushort* kbase = Kb + (size_t)kvh * T * HD_;
  const ushort* vbase = Vt + (size_t)kvh * HD_ * T;

  // staging registers (prefetch buffer): 8 x uint4 = 32 VGPRs
  uint4 kl[4], vl[4];
  {
    int t0 = p << 6;
#pragma unroll
    for (int j = 0; j < 4; ++j) {
      int i = tid + j * 256;
      int r = i >> 4, c = (i & 15) << 3;
      kl[j] = *(const uint4*)(kbase + (size_t)(t0 + r) * HD_ + c);
    }
#pragma unroll
    for (int j = 0; j < 4; ++j) {
      int i = tid + j * 256;
      int d = i >> 3, c = (i & 7) << 3;
      vl[j] = *(const uint4*)(vbase + (size_t)d * T + t0 + c);
    }
  }

  for (int it = p; it < ntb; it += 2) {
    int t0 = it << 6;
    // ---- stage prefetched regs -> LDS ----
#pragma unroll
    for (int j = 0; j < 4; ++j) {
      int i = tid + j * 256;
      int r = i >> 4, c = (i & 15) << 3;
      *(uint4*)&lK[r * LKS + c] = kl[j];
    }
#pragma unroll
    for (int j = 0; j < 4; ++j) {
      int i = tid + j * 256;
      int d = i >> 3, c = (i & 7) << 3;
      *(uint4*)&lV[d * LVS + c] = vl[j];
    }
    // ---- issue next tile's global loads (latency hidden behind compute) ----
    if (it + 2 < ntb) {
      int t2 = (it + 2) << 6;
#pragma unroll
      for (int j = 0; j < 4; ++j) {
        int i = tid + j * 256;
        int r = i >> 4, c = (i & 15) << 3;
        kl[j] = *(const uint4*)(kbase + (size_t)(t2 + r) * HD_ + c);
      }
#pragma unroll
      for (int j = 0; j < 4; ++j) {
        int i = tid + j * 256;
        int d = i >> 3, c = (i & 7) << 3;
        vl[j] = *(const uint4*)(vbase + (size_t)d * T + t2 + c);
      }
    }
    __syncthreads();                               // A: staging visible

    bool active = (t0 <= CHUNK_ + q0 + 32 * w + 31);
    uint2 pw[2][4];
    if (active) {
      f32x4 s_[4][2];
#pragma unroll
      for (int tt = 0; tt < 4; ++tt)
#pragma unroll
        for (int nt = 0; nt < 2; ++nt) s_[tt][nt] = f32x4{0.f, 0.f, 0.f, 0.f};
#pragma unroll
      for (int tt = 0; tt < 4; ++tt) {
        bf16x8 kf[4];
#pragma unroll
        for (int kt = 0; kt < 4; ++kt)
          kf[kt] = *(const bf16x8*)&lK[(l16 + 16 * tt) * LKS + kt * 32 + quad * 8];
#pragma unroll
        for (int nt = 0; nt < 2; ++nt)
#pragma unroll
          for (int kt = 0; kt < 4; ++kt)
            s_[tt][nt] = __builtin_amdgcn_mfma_f32_16x16x32_bf16(kf[kt], qf[nt][kt], s_[tt][nt], 0, 0, 0);
      }
      bool need_mask = (t0 + BK - 1) > (CHUNK_ + q0 + 32 * w);
#pragma unroll
      for (int nt = 0; nt < 2; ++nt) {
        int qp = qpos0 + nt * 16;
        float mx = -3.0e38f;
#pragma unroll
        for (int tt = 0; tt < 4; ++tt)
#pragma unroll
          for (int r = 0; r < 4; ++r) {
            float sv = s_[tt][nt][r] * sc;
            if (need_mask) {
              int t = t0 + tt * 16 + quad * 4 + r;
              sv = (t > qp) ? -3.0e38f : sv;
            }
            s_[tt][nt][r] = sv;
            mx = fmaxf(mx, sv);
          }
        mx = fmaxf(mx, __shfl_xor(mx, 16));
        mx = fmaxf(mx, __shfl_xor(mx, 32));
        float mnew  = fmaxf(m[nt], mx);
        float alpha = exp2f(m[nt] - mnew);
        m[nt] = mnew;
        float sum = 0.f;
#pragma unroll
        for (int tt = 0; tt < 4; ++tt) {
          f32x4 pv;
#pragma unroll
          for (int r = 0; r < 4; ++r) {
            float pe = exp2f(s_[tt][nt][r] - mnew);
            pv[r] = pe;
            sum += pe;
          }
          uint2 u;
          u.x = (unsigned)f2bf(pv[0]) | ((unsigned)f2bf(pv[1]) << 16);
          u.y = (unsigned)f2bf(pv[2]) | ((unsigned)f2bf(pv[3]) << 16);
          pw[nt][tt] = u;
        }
        sum += __shfl_xor(sum, 16);
        sum += __shfl_xor(sum, 32);
        l[nt] = l[nt] * alpha + sum;
#pragma unroll
        for (int d8 = 0; d8 < 8; ++d8) o[nt][d8] *= alpha;
      }
    }
    __syncthreads();                               // B: all lK reads done

    if (active) {
#pragma unroll
      for (int nt = 0; nt < 2; ++nt)
#pragma unroll
        for (int tt = 0; tt < 4; ++tt)
          *(uint2*)&lP[(nt * 16 + l16) * LPS + tt * 16 + quad * 4] = pw[nt][tt];
      bf16x8 pf[2][2];
#pragma unroll
      for (int nt = 0; nt < 2; ++nt)
#pragma unroll
        for (int kt2 = 0; kt2 < 2; ++kt2) {
          int off = (nt * 16 + l16) * LPS + kt2 * 32 + quad * 8;
          uint2 a = *(const uint2*)&lP[off];
          uint2 b = *(const uint2*)&lP[off + 4];
          uint4 u = make_uint4(a.x, a.y, b.x, b.y);
          pf[nt][kt2] = __builtin_bit_cast(bf16x8, u);
        }
#pragma unroll
      for (int d8 = 0; d8 < 8; ++d8) {
        bf16x8 vf[2];
#pragma unroll
        for (int kt2 = 0; kt2 < 2; ++kt2)
          vf[kt2] = *(const bf16x8*)&lV[(d8 * 16 + l16) * LVS + kt2 * 32 + quad * 8];
#pragma unroll
        for (int nt = 0; nt < 2; ++nt)
#pragma unroll
          for (int kt2 = 0; kt2 < 2; ++kt2)
            o[nt][d8] = __builtin_amdgcn_mfma_f32_16x16x32_bf16(vf[kt2], pf[nt][kt2], o[nt][d8], 0, 0, 0);
      }
    }
    __syncthreads();                               // C: lP/lV reads done -> safe to restage
  }

  // epilogue: normalized partial + (m,l)
  float* OUT = p ? O1 : O0;
#pragma unroll
  for (int nt = 0; nt < 2; ++nt) {
    int qg = q0 + 32 * w + nt * 16 + l16;
    float invl = 1.0f / l[nt];
#pragma unroll
    for (int d8 = 0; d8 < 8; ++d8) {
      f32x4 r = o[nt][d8] * invl;
      *(float4*)&OUT[((size_t)qg * H_ + h) * HD_ + d8 * 16 + quad * 4] =
          make_float4(r[0], r[1], r[2], r[3]);
    }
    if (quad == 0) {
      float* mlp = ML + ((size_t)qg * H_ + h) * 4 + p * 2;
      mlp[0] = m[nt];
      mlp[1] = l[nt];
    }
  }
}

// ---------- combine: out = (w0*o0 + w1*o1) with w_p = exp2(m_p - m) * l_p ----------
__global__ void combine(float* __restrict__ out, const float* __restrict__ O1,
                        const float* __restrict__ ML) {
  int idx = blockIdx.x * 256 + threadIdx.x;   // float4 index
  int qh = idx >> 5;                          // 32 float4 per (q,h)
  float4 o0 = ((const float4*)out)[idx];
  float4 o1 = ((const float4*)O1)[idx];
  float m0 = ML[qh * 4 + 0], l0 = ML[qh * 4 + 1];
  float m1 = ML[qh * 4 + 2], l1 = ML[qh * 4 + 3];
  float m  = fmaxf(m0, m1);
  float w0 = exp2f(m0 - m) * l0;
  float w1 = exp2f(m1 - m) * l1;
  float inv = 1.0f / (w0 + w1);
  w0 *= inv; w1 *= inv;
  ((float4*)out)[idx] = make_float4(o0.x * w0 + o1.x * w1, o0.y * w0 + o1.y * w1,
                                    o0.z * w0 + o1.z * w1, o0.w * w0 + o1.w * w1);
}

extern "C" void kernel_launch(void* const* d_in, const int* in_sizes, int n_in,
                              void* d_out, int out_size, void* d_ws, size_t ws_size,
                              hipStream_t stream) {
  const float* q  = (const float*)d_in[0];
  const float* k  = (const float*)d_in[1];
  const float* v  = (const float*)d_in[2];
  const float* kc = (const float*)d_in[3];
  const float* vc = (const float*)d_in[4];
  const int* slots = (const int*)d_in[5];

  int N = in_sizes[5];
  int T = CHUNK_ + N;
  int nq = N / BQ;

  ushort* Kb = (ushort*)d_ws;                              // [KVH][T][HD]
  ushort* Vt = Kb + (size_t)KVH_ * T * HD_;                // [KVH][HD][T]
  float*  O1 = (float*)(Vt + (size_t)KVH_ * HD_ * T);      // [N][H][HD]
  float*  ML = O1 + (size_t)N * H_ * HD_;                  // [N*H][4]
  float* out = (float*)d_out;

  prep<<<dim3(T / 64, KVH_), 256, 0, stream>>>(kc, vc, k, v, slots, Kb, Vt, T);
  fa_kernel<<<dim3(H_, nq, 2), 256, 0, stream>>>(q, Kb, Vt, out, O1, ML, N, T);
  combine<<<(N * H_ * HD_) / 1024, 256, 0, stream>>>(out, O1, ML);
}